// Round 19
// baseline (335.545 us; speedup 1.0000x reference)
//
#include <hip/hip_runtime.h>
#include <math.h>

#define J   29
#define CH  3
#define JC  87            // J*CH
#define E0  56
#define B   256
#define T   1024
#define FRAMES (B*T)      // 262144
#define FPC 64            // frames per chunk (= lanes)
#define CPB 2             // chunks per block
#define NBLK (FRAMES/(FPC*CPB)) // 2048
#define CHUNK_F4 1392     // float4s per chunk (22272 B)
#define BPB (T/(FPC*CPB)) // 8 blocks per batch
#define SLOTS 4           // padded nnz per row (overflow beyond)
#define PROWS 32          // padded row count
#define MAXOV 96          // overflow capacity
#define WAVES 8
#define RPW 4             // rows per wave

// ---- prep: identical to R14/R18 (proven) ------------------------------------
__global__ void prep_kernel(const int* __restrict__ ei,
                            int2* __restrict__ pairs,
                            int*  __restrict__ ov_rp,
                            int2* __restrict__ ov_pairs)
{
    __shared__ float M[J * J];
    __shared__ float dinv[J];
    __shared__ int   cnt_ov[J];
    int tid = threadIdx.x;

    for (int i = tid; i < J * J; i += 64) M[i] = 0.f;
    if (tid < J) {
        int d = 1;
        for (int e = 0; e < E0; ++e) d += (ei[E0 + e] == tid) ? 1 : 0;
        dinv[tid] = rsqrtf((float)d);
    }
    __syncthreads();

    if (tid < J) {
        for (int e = 0; e < E0; ++e) {
            if (ei[E0 + e] == tid) {
                int s = ei[e];
                M[tid * J + s] += dinv[s] * dinv[tid];
            }
        }
        M[tid * J + tid] += dinv[tid] * dinv[tid];
        int c = 0;
        for (int i = 0; i < J; ++i) c += (M[tid * J + i] != 0.f) ? 1 : 0;
        cnt_ov[tid] = (c > SLOTS) ? (c - SLOTS) : 0;
    }
    __syncthreads();

    if (tid == 0) {
        int a = 0;
        for (int j = 0; j < J; ++j) { ov_rp[j] = a; a += cnt_ov[j]; }
        for (int j = J; j <= 32; ++j) ov_rp[j] = a;
    }
    __syncthreads();

    if (tid < PROWS) {
        int2 zero; zero.x = 0; zero.y = 0;
        if (tid < J) {
            int s = 0, p = ov_rp[tid];
            for (int i = 0; i < J; ++i) {
                float v = M[tid * J + i];
                if (v != 0.f) {
                    if (s < SLOTS) {
                        int2 pr; pr.x = i * 12; pr.y = __float_as_int(v);
                        pairs[tid * SLOTS + s] = pr;
                    } else {
                        int2 pr; pr.x = (tid << 16) | (i * 12); pr.y = __float_as_int(v);
                        ov_pairs[p++] = pr;
                    }
                    ++s;
                }
            }
            for (; s < SLOTS; ++s) pairs[tid * SLOTS + s] = zero;
        } else {
            for (int s = 0; s < SLOTS; ++s) pairs[tid * SLOTS + s] = zero;
        }
    }
    __syncthreads();
    if (tid == 0) {
        int a = ov_rp[J];
        for (int i = a; i < MAXOV; ++i) { int2 pr; pr.x = 0; pr.y = 0; ov_pairs[i] = pr; }
    }
}

// ---- main: R18 dbuf body, CPB=2, fused finalize via device atomics ----------
__global__ __launch_bounds__(512, 2)
void gcn_main(const float* __restrict__ x,
              const float* __restrict__ Wp,
              const float* __restrict__ bp,
              const int2* __restrict__ pairs,
              const int*  __restrict__ ov_rp,
              const int2* __restrict__ ov_pairs,
              const float* __restrict__ fcW,
              const float* __restrict__ fcb,
              float* __restrict__ hsum,     // [B*JC] zeroed each launch
              int*   __restrict__ cnt,      // [B]    zeroed each launch
              float* __restrict__ out) {
    __shared__ float4 xs4[2][CHUNK_F4];   // 2 x 22272 B
    __shared__ int2   s_ov[MAXOV];
    __shared__ float  hs[JC];
    __shared__ int    s_old;

    int tid  = threadIdx.x;
    int lane = tid & 63;
    int wv   = tid >> 6;
    int rowbase = __builtin_amdgcn_readfirstlane(wv * RPW);

    float sW[9], sb[CH];
#pragma unroll
    for (int i = 0; i < 9; ++i) sW[i] = Wp[i];
#pragma unroll
    for (int i = 0; i < CH; ++i) sb[i] = bp[i];
    int ov0 = ov_rp[rowbase], ov1 = ov_rp[rowbase + RPW];
    if (tid < MAXOV) s_ov[tid] = ov_pairs[tid];

    const float4* src4 = (const float4*)x + (size_t)blockIdx.x * (CPB * CHUNK_F4);
    int i2 = 1024 + tid; if (i2 > CHUNK_F4 - 1) i2 = CHUNK_F4 - 1;

    // prologue: chunk 0 -> regs -> buf0; chunk 1 issued before first barrier
    float4 pfA0 = src4[tid], pfA1 = src4[512 + tid], pfA2 = src4[i2];
    xs4[0][tid] = pfA0; xs4[0][512 + tid] = pfA1; xs4[0][i2] = pfA2;
    const float4* s1 = src4 + CHUNK_F4;
    float4 pfB0 = s1[tid], pfB1 = s1[512 + tid], pfB2 = s1[i2];

    float acc[RPW][CH];
#pragma unroll
    for (int r = 0; r < RPW; ++r)
#pragma unroll
        for (int c = 0; c < CH; ++c) acc[r][c] = 0.f;

    __syncthreads();   // buf0 + s_ov visible

#define COMPUTE_CHUNK(BUF)                                                    \
    {                                                                         \
        const char* xf = (const char*)xs4[BUF] + lane * 348;                  \
        float y[RPW][CH];                                                     \
        _Pragma("unroll")                                                     \
        for (int R = 0; R < RPW; ++R) {                                       \
            float a0 = 0.f, a1 = 0.f, a2 = 0.f;                               \
            _Pragma("unroll")                                                 \
            for (int sl = 0; sl < SLOTS; ++sl) {                              \
                int2 pr = pairs[(rowbase + R) * SLOTS + sl];                  \
                float v = __int_as_float(pr.y);                               \
                const float* q = (const float*)(xf + pr.x);                   \
                a0 += v * q[0]; a1 += v * q[1]; a2 += v * q[2];               \
            }                                                                 \
            y[R][0] = a0; y[R][1] = a1; y[R][2] = a2;                         \
        }                                                                     \
        for (int e = ov0; e < ov1; ++e) {                                     \
            int2 pr = s_ov[e];                                                \
            int row = pr.x >> 16; int off = pr.x & 0xFFFF;                    \
            float v = __int_as_float(pr.y);                                   \
            const float* q = (const float*)(xf + off);                        \
            float d0 = v * q[0], d1 = v * q[1], d2 = v * q[2];                \
            _Pragma("unroll")                                                 \
            for (int R = 0; R < RPW; ++R)                                     \
                if (row == rowbase + R) { y[R][0] += d0; y[R][1] += d1; y[R][2] += d2; } \
        }                                                                     \
        _Pragma("unroll")                                                     \
        for (int R = 0; R < RPW; ++R)                                         \
            _Pragma("unroll")                                                 \
            for (int ch = 0; ch < CH; ++ch) {                                 \
                float t = y[R][0] * sW[0 * CH + ch]                           \
                        + y[R][1] * sW[1 * CH + ch]                           \
                        + y[R][2] * sW[2 * CH + ch]                           \
                        + sb[ch];                                             \
                acc[R][ch] += fmaxf(t, 0.f);                                  \
            }                                                                 \
    }

    // CPB=2: compute buf0 while chunk1 flies, write+barrier, compute buf1
    COMPUTE_CHUNK(0);
    xs4[1][tid] = pfB0; xs4[1][512 + tid] = pfB1; xs4[1][i2] = pfB2;
    __syncthreads();
    COMPUTE_CHUNK(1);

    // ---- epilogue: transpose + column reduce -> atomic hsum ----------------
    __syncthreads();
    float* red = (float*)xs4[0];
#pragma unroll
    for (int R = 0; R < RPW; ++R) {
        int j = rowbase + R;
        if (j < J) {
#pragma unroll
            for (int ch = 0; ch < CH; ++ch)
                red[lane * JC + j * CH + ch] = acc[R][ch];
        }
    }
    __syncthreads();

    int batch = blockIdx.x / BPB;
    if (tid < JC) {
        float a = 0.f;
#pragma unroll
        for (int L = 0; L < FPC; ++L) a += red[L * JC + tid];
        atomicAdd(&hsum[batch * JC + tid], a);
    }
    __threadfence();
    __syncthreads();
    if (tid == 0) s_old = atomicAdd(&cnt[batch], 1);
    __syncthreads();

    if (s_old == BPB - 1) {   // last block of this batch: emit h and z
        if (tid < JC) {
            float v = atomicAdd(&hsum[batch * JC + tid], 0.0f);  // coherent read
            v *= (1.0f / (float)T);
            hs[tid] = v;
            out[(size_t)batch * JC + tid] = v;
        }
        __syncthreads();
        if (tid < 2) {
            float a = fcb[tid];
            for (int r = 0; r < JC; ++r) a += hs[r] * fcW[r * 2 + tid];
            out[(size_t)B * JC + batch * 2 + tid] = 1.0f / (1.0f + expf(-a));
        }
    }
}

extern "C" void kernel_launch(void* const* d_in, const int* in_sizes, int n_in,
                              void* d_out, int out_size, void* d_ws, size_t ws_size,
                              hipStream_t stream) {
    const float* x   = (const float*)d_in[0];
    const int*   ei  = (const int*)d_in[1];
    const float* W   = (const float*)d_in[4];
    const float* bb  = (const float*)d_in[5];
    const float* fcW = (const float*)d_in[6];
    const float* fcb = (const float*)d_in[7];

    char* ws = (char*)d_ws;
    int2*  pairs    = (int2*)ws;                      // 128 * 8B
    int2*  ov_pairs = pairs + PROWS * SLOTS;          // 96 * 8B
    int*   ov_rp    = (int*)(ov_pairs + MAXOV);       // 33 * 4B
    float* hsum     = (float*)(ws + 8192);            // B*JC floats = 89088 B
    int*   cnt      = (int*)(ws + 8192 + B * JC * 4); // B ints

    // zero the accumulation state (harness does not re-poison between replays)
    hipMemsetAsync(ws + 8192, 0, B * JC * 4 + B * 4, stream);

    prep_kernel<<<1, 64, 0, stream>>>(ei, pairs, ov_rp, ov_pairs);
    gcn_main<<<NBLK, WAVES * 64, 0, stream>>>(x, W, bb, pairs, ov_rp, ov_pairs,
                                              fcW, fcb, hsum, cnt, (float*)d_out);
}

// Round 20
// 52.131 us; speedup vs baseline: 6.4366x; 6.4366x over previous
//
#include <hip/hip_runtime.h>
#include <math.h>

#define J   29
#define CH  3
#define JC  87            // J*CH
#define E0  56
#define B   256
#define T   1024
#define FRAMES (B*T)      // 262144
#define FPC 64            // frames per chunk (= lanes)
#define CPB 2             // chunks per block
#define NBLK (FRAMES/(FPC*CPB)) // 2048
#define CHUNK_F4 1392     // float4s per chunk (22272 B)
#define BPB (T/(FPC*CPB)) // 8 blocks per batch
#define SLOTS 4           // padded nnz per row (overflow beyond)
#define PROWS 32          // padded row count
#define MAXOV 96          // overflow capacity
#define WAVES 8
#define RPW 4             // rows per wave

// ---- prep: identical to R14/R18 (proven) ------------------------------------
__global__ void prep_kernel(const int* __restrict__ ei,
                            int2* __restrict__ pairs,
                            int*  __restrict__ ov_rp,
                            int2* __restrict__ ov_pairs)
{
    __shared__ float M[J * J];
    __shared__ float dinv[J];
    __shared__ int   cnt_ov[J];
    int tid = threadIdx.x;

    for (int i = tid; i < J * J; i += 64) M[i] = 0.f;
    if (tid < J) {
        int d = 1;
        for (int e = 0; e < E0; ++e) d += (ei[E0 + e] == tid) ? 1 : 0;
        dinv[tid] = rsqrtf((float)d);
    }
    __syncthreads();

    if (tid < J) {
        for (int e = 0; e < E0; ++e) {
            if (ei[E0 + e] == tid) {
                int s = ei[e];
                M[tid * J + s] += dinv[s] * dinv[tid];
            }
        }
        M[tid * J + tid] += dinv[tid] * dinv[tid];
        int c = 0;
        for (int i = 0; i < J; ++i) c += (M[tid * J + i] != 0.f) ? 1 : 0;
        cnt_ov[tid] = (c > SLOTS) ? (c - SLOTS) : 0;
    }
    __syncthreads();

    if (tid == 0) {
        int a = 0;
        for (int j = 0; j < J; ++j) { ov_rp[j] = a; a += cnt_ov[j]; }
        for (int j = J; j <= 32; ++j) ov_rp[j] = a;
    }
    __syncthreads();

    if (tid < PROWS) {
        int2 zero; zero.x = 0; zero.y = 0;
        if (tid < J) {
            int s = 0, p = ov_rp[tid];
            for (int i = 0; i < J; ++i) {
                float v = M[tid * J + i];
                if (v != 0.f) {
                    if (s < SLOTS) {
                        int2 pr; pr.x = i * 12; pr.y = __float_as_int(v);
                        pairs[tid * SLOTS + s] = pr;
                    } else {
                        int2 pr; pr.x = (tid << 16) | (i * 12); pr.y = __float_as_int(v);
                        ov_pairs[p++] = pr;
                    }
                    ++s;
                }
            }
            for (; s < SLOTS; ++s) pairs[tid * SLOTS + s] = zero;
        } else {
            for (int s = 0; s < SLOTS; ++s) pairs[tid * SLOTS + s] = zero;
        }
    }
    __syncthreads();
    if (tid == 0) {
        int a = ov_rp[J];
        for (int i = a; i < MAXOV; ++i) { int2 pr; pr.x = 0; pr.y = 0; ov_pairs[i] = pr; }
    }
}

// ---- main: R18 dbuf body, CPB=2, fused finalize (NO threadfence) -----------
__global__ __launch_bounds__(512, 2)
void gcn_main(const float* __restrict__ x,
              const float* __restrict__ Wp,
              const float* __restrict__ bp,
              const int2* __restrict__ pairs,
              const int*  __restrict__ ov_rp,
              const int2* __restrict__ ov_pairs,
              const float* __restrict__ fcW,
              const float* __restrict__ fcb,
              float* __restrict__ hsum,     // [B*JC] zeroed each launch
              int*   __restrict__ cnt,      // [B]    zeroed each launch
              float* __restrict__ out) {
    __shared__ float4 xs4[2][CHUNK_F4];   // 2 x 22272 B
    __shared__ int2   s_ov[MAXOV];
    __shared__ float  hs[JC];
    __shared__ int    s_old;

    int tid  = threadIdx.x;
    int lane = tid & 63;
    int wv   = tid >> 6;
    int rowbase = __builtin_amdgcn_readfirstlane(wv * RPW);

    float sW[9], sb[CH];
#pragma unroll
    for (int i = 0; i < 9; ++i) sW[i] = Wp[i];
#pragma unroll
    for (int i = 0; i < CH; ++i) sb[i] = bp[i];
    int ov0 = ov_rp[rowbase], ov1 = ov_rp[rowbase + RPW];
    if (tid < MAXOV) s_ov[tid] = ov_pairs[tid];

    const float4* src4 = (const float4*)x + (size_t)blockIdx.x * (CPB * CHUNK_F4);
    int i2 = 1024 + tid; if (i2 > CHUNK_F4 - 1) i2 = CHUNK_F4 - 1;

    // prologue: chunk 0 -> regs -> buf0; chunk 1 issued before first barrier
    float4 pfA0 = src4[tid], pfA1 = src4[512 + tid], pfA2 = src4[i2];
    xs4[0][tid] = pfA0; xs4[0][512 + tid] = pfA1; xs4[0][i2] = pfA2;
    const float4* s1 = src4 + CHUNK_F4;
    float4 pfB0 = s1[tid], pfB1 = s1[512 + tid], pfB2 = s1[i2];

    float acc[RPW][CH];
#pragma unroll
    for (int r = 0; r < RPW; ++r)
#pragma unroll
        for (int c = 0; c < CH; ++c) acc[r][c] = 0.f;

    __syncthreads();   // buf0 + s_ov visible

#define COMPUTE_CHUNK(BUF)                                                    \
    {                                                                         \
        const char* xf = (const char*)xs4[BUF] + lane * 348;                  \
        float y[RPW][CH];                                                     \
        _Pragma("unroll")                                                     \
        for (int R = 0; R < RPW; ++R) {                                       \
            float a0 = 0.f, a1 = 0.f, a2 = 0.f;                               \
            _Pragma("unroll")                                                 \
            for (int sl = 0; sl < SLOTS; ++sl) {                              \
                int2 pr = pairs[(rowbase + R) * SLOTS + sl];                  \
                float v = __int_as_float(pr.y);                               \
                const float* q = (const float*)(xf + pr.x);                   \
                a0 += v * q[0]; a1 += v * q[1]; a2 += v * q[2];               \
            }                                                                 \
            y[R][0] = a0; y[R][1] = a1; y[R][2] = a2;                         \
        }                                                                     \
        for (int e = ov0; e < ov1; ++e) {                                     \
            int2 pr = s_ov[e];                                                \
            int row = pr.x >> 16; int off = pr.x & 0xFFFF;                    \
            float v = __int_as_float(pr.y);                                   \
            const float* q = (const float*)(xf + off);                        \
            float d0 = v * q[0], d1 = v * q[1], d2 = v * q[2];                \
            _Pragma("unroll")                                                 \
            for (int R = 0; R < RPW; ++R)                                     \
                if (row == rowbase + R) { y[R][0] += d0; y[R][1] += d1; y[R][2] += d2; } \
        }                                                                     \
        _Pragma("unroll")                                                     \
        for (int R = 0; R < RPW; ++R)                                         \
            _Pragma("unroll")                                                 \
            for (int ch = 0; ch < CH; ++ch) {                                 \
                float t = y[R][0] * sW[0 * CH + ch]                           \
                        + y[R][1] * sW[1 * CH + ch]                           \
                        + y[R][2] * sW[2 * CH + ch]                           \
                        + sb[ch];                                             \
                acc[R][ch] += fmaxf(t, 0.f);                                  \
            }                                                                 \
    }

    // CPB=2: compute buf0 while chunk1 flies, write+barrier, compute buf1
    COMPUTE_CHUNK(0);
    xs4[1][tid] = pfB0; xs4[1][512 + tid] = pfB1; xs4[1][i2] = pfB2;
    __syncthreads();
    COMPUTE_CHUNK(1);

    // ---- epilogue: transpose + column reduce -> atomic hsum ----------------
    __syncthreads();
    float* red = (float*)xs4[0];
#pragma unroll
    for (int R = 0; R < RPW; ++R) {
        int j = rowbase + R;
        if (j < J) {
#pragma unroll
            for (int ch = 0; ch < CH; ++ch)
                red[lane * JC + j * CH + ch] = acc[R][ch];
        }
    }
    __syncthreads();

    int batch = blockIdx.x / BPB;
    if (tid < JC) {
        float a = 0.f;
#pragma unroll
        for (int L = 0; L < FPC; ++L) a += red[L * JC + tid];
        // RETURNING atomic: vmcnt tracks completion at the coherent point
        float old = atomicAdd(&hsum[batch * JC + tid], a);
        asm volatile("" :: "v"(old));          // keep the return alive
    }
    // order: all hsum adds performed before the cnt election (NO L2 flush)
    asm volatile("s_waitcnt vmcnt(0)" ::: "memory");
    __syncthreads();
    if (tid == 0) s_old = atomicAdd(&cnt[batch], 1);
    __syncthreads();

    if (s_old == BPB - 1) {   // last block of this batch: emit h and z
        if (tid < JC) {
            float v = atomicAdd(&hsum[batch * JC + tid], 0.0f);  // coherent read
            v *= (1.0f / (float)T);
            hs[tid] = v;
            out[(size_t)batch * JC + tid] = v;
        }
        __syncthreads();
        if (tid < 2) {
            float a = fcb[tid];
            for (int r = 0; r < JC; ++r) a += hs[r] * fcW[r * 2 + tid];
            out[(size_t)B * JC + batch * 2 + tid] = 1.0f / (1.0f + expf(-a));
        }
    }
}

extern "C" void kernel_launch(void* const* d_in, const int* in_sizes, int n_in,
                              void* d_out, int out_size, void* d_ws, size_t ws_size,
                              hipStream_t stream) {
    const float* x   = (const float*)d_in[0];
    const int*   ei  = (const int*)d_in[1];
    const float* W   = (const float*)d_in[4];
    const float* bb  = (const float*)d_in[5];
    const float* fcW = (const float*)d_in[6];
    const float* fcb = (const float*)d_in[7];

    char* ws = (char*)d_ws;
    int2*  pairs    = (int2*)ws;                      // 128 * 8B
    int2*  ov_pairs = pairs + PROWS * SLOTS;          // 96 * 8B
    int*   ov_rp    = (int*)(ov_pairs + MAXOV);       // 33 * 4B
    float* hsum     = (float*)(ws + 8192);            // B*JC floats = 89088 B
    int*   cnt      = (int*)(ws + 8192 + B * JC * 4); // B ints

    // zero the accumulation state (harness does not re-poison between replays)
    hipMemsetAsync(ws + 8192, 0, B * JC * 4 + B * 4, stream);

    prep_kernel<<<1, 64, 0, stream>>>(ei, pairs, ov_rp, ov_pairs);
    gcn_main<<<NBLK, WAVES * 64, 0, stream>>>(x, W, bb, pairs, ov_rp, ov_pairs,
                                              fcW, fcb, hsum, cnt, (float*)d_out);
}

// Round 21
// 42.542 us; speedup vs baseline: 7.8873x; 1.2254x over previous
//
#include <hip/hip_runtime.h>
#include <math.h>

#define J   29
#define CH  3
#define JC  87            // J*CH
#define E0  56
#define B   256
#define T   1024
#define FRAMES (B*T)      // 262144
#define FPC 64            // frames per chunk (= lanes)
#define CPB 4             // chunks per block (even)
#define NBLK (FRAMES/(FPC*CPB)) // 1024
#define CHUNK_F4 1392     // float4s per chunk (22272 B)
#define BPB (T/(FPC*CPB)) // 4 partials per batch
#define SLOTS 4           // padded nnz per row (overflow beyond)
#define PROWS 32          // padded row count
#define MAXOV 96          // overflow capacity
#define WAVES 8
#define RPW 4             // rows per wave

// ---- prep: identical to R14/R18 (proven) ------------------------------------
__global__ void prep_kernel(const int* __restrict__ ei,
                            int2* __restrict__ pairs,
                            int*  __restrict__ ov_rp,
                            int2* __restrict__ ov_pairs)
{
    __shared__ float M[J * J];
    __shared__ float dinv[J];
    __shared__ int   cnt_ov[J];
    int tid = threadIdx.x;

    for (int i = tid; i < J * J; i += 64) M[i] = 0.f;
    if (tid < J) {
        int d = 1;
        for (int e = 0; e < E0; ++e) d += (ei[E0 + e] == tid) ? 1 : 0;
        dinv[tid] = rsqrtf((float)d);
    }
    __syncthreads();

    if (tid < J) {
        for (int e = 0; e < E0; ++e) {
            if (ei[E0 + e] == tid) {
                int s = ei[e];
                M[tid * J + s] += dinv[s] * dinv[tid];
            }
        }
        M[tid * J + tid] += dinv[tid] * dinv[tid];
        int c = 0;
        for (int i = 0; i < J; ++i) c += (M[tid * J + i] != 0.f) ? 1 : 0;
        cnt_ov[tid] = (c > SLOTS) ? (c - SLOTS) : 0;
    }
    __syncthreads();

    if (tid == 0) {
        int a = 0;
        for (int j = 0; j < J; ++j) { ov_rp[j] = a; a += cnt_ov[j]; }
        for (int j = J; j <= 32; ++j) ov_rp[j] = a;
    }
    __syncthreads();

    if (tid < PROWS) {
        int2 zero; zero.x = 0; zero.y = 0;
        if (tid < J) {
            int s = 0, p = ov_rp[tid];
            for (int i = 0; i < J; ++i) {
                float v = M[tid * J + i];
                if (v != 0.f) {
                    if (s < SLOTS) {
                        int2 pr; pr.x = i * 12; pr.y = __float_as_int(v);
                        pairs[tid * SLOTS + s] = pr;
                    } else {
                        int2 pr; pr.x = (tid << 16) | (i * 12); pr.y = __float_as_int(v);
                        ov_pairs[p++] = pr;
                    }
                    ++s;
                }
            }
            for (; s < SLOTS; ++s) pairs[tid * SLOTS + s] = zero;
        } else {
            for (int s = 0; s < SLOTS; ++s) pairs[tid * SLOTS + s] = zero;
        }
    }
    __syncthreads();
    if (tid == 0) {
        int a = ov_rp[J];
        for (int i = a; i < MAXOV; ++i) { int2 pr; pr.x = 0; pr.y = 0; ov_pairs[i] = pr; }
    }
}

// ---- main: R18 dbuf body + RAW barriers (no vmcnt drain in the loop) --------
__global__ __launch_bounds__(512, 2)
void gcn_main(const float* __restrict__ x,
              const float* __restrict__ Wp,
              const float* __restrict__ bp,
              const int2* __restrict__ pairs,
              const int*  __restrict__ ov_rp,
              const int2* __restrict__ ov_pairs,
              float* __restrict__ partials) {
    __shared__ float4 xs4[2][CHUNK_F4];   // 2 x 22272 B
    __shared__ int2   s_ov[MAXOV];

    int tid  = threadIdx.x;
    int lane = tid & 63;
    int wv   = tid >> 6;
    int rowbase = __builtin_amdgcn_readfirstlane(wv * RPW);

    float sW[9], sb[CH];
#pragma unroll
    for (int i = 0; i < 9; ++i) sW[i] = Wp[i];
#pragma unroll
    for (int i = 0; i < CH; ++i) sb[i] = bp[i];
    int ov0 = ov_rp[rowbase], ov1 = ov_rp[rowbase + RPW];
    if (tid < MAXOV) s_ov[tid] = ov_pairs[tid];   // issued BEFORE pf loads (oldest)

    const float4* src4 = (const float4*)x + (size_t)blockIdx.x * (CPB * CHUNK_F4);
    int i2 = 1024 + tid; if (i2 > CHUNK_F4 - 1) i2 = CHUNK_F4 - 1;

    // prologue: chunks 0 and 1 in flight (depth-2)
    float4 pfA0 = src4[tid], pfA1 = src4[512 + tid], pfA2 = src4[i2];
    const float4* s1 = src4 + CHUNK_F4;
    float4 pfB0 = s1[tid], pfB1 = s1[512 + tid], pfB2 = s1[i2];

    float acc[RPW][CH];
#pragma unroll
    for (int r = 0; r < RPW; ++r)
#pragma unroll
        for (int c = 0; c < CH; ++c) acc[r][c] = 0.f;

#define COMPUTE_CHUNK(BUF)                                                    \
    {                                                                         \
        const char* xf = (const char*)xs4[BUF] + lane * 348;                  \
        float y[RPW][CH];                                                     \
        _Pragma("unroll")                                                     \
        for (int R = 0; R < RPW; ++R) {                                       \
            float a0 = 0.f, a1 = 0.f, a2 = 0.f;                               \
            _Pragma("unroll")                                                 \
            for (int sl = 0; sl < SLOTS; ++sl) {                              \
                int2 pr = pairs[(rowbase + R) * SLOTS + sl];                  \
                float v = __int_as_float(pr.y);                               \
                const float* q = (const float*)(xf + pr.x);                   \
                a0 += v * q[0]; a1 += v * q[1]; a2 += v * q[2];               \
            }                                                                 \
            y[R][0] = a0; y[R][1] = a1; y[R][2] = a2;                         \
        }                                                                     \
        for (int e = ov0; e < ov1; ++e) {                                     \
            int2 pr = s_ov[e];                                                \
            int row = pr.x >> 16; int off = pr.x & 0xFFFF;                    \
            float v = __int_as_float(pr.y);                                   \
            const float* q = (const float*)(xf + off);                        \
            float d0 = v * q[0], d1 = v * q[1], d2 = v * q[2];                \
            _Pragma("unroll")                                                 \
            for (int R = 0; R < RPW; ++R)                                     \
                if (row == rowbase + R) { y[R][0] += d0; y[R][1] += d1; y[R][2] += d2; } \
        }                                                                     \
        _Pragma("unroll")                                                     \
        for (int R = 0; R < RPW; ++R)                                         \
            _Pragma("unroll")                                                 \
            for (int ch = 0; ch < CH; ++ch) {                                 \
                float t = y[R][0] * sW[0 * CH + ch]                           \
                        + y[R][1] * sW[1 * CH + ch]                           \
                        + y[R][2] * sW[2 * CH + ch]                           \
                        + sb[ch];                                             \
                acc[R][ch] += fmaxf(t, 0.f);                                  \
            }                                                                 \
    }

// raw barrier: LDS writes flushed (lgkmcnt only), vmem prefetch stays in flight
#define RAW_BARRIER()                                                         \
    asm volatile("s_waitcnt lgkmcnt(0)" ::: "memory");                        \
    __builtin_amdgcn_s_barrier();                                             \
    __builtin_amdgcn_sched_barrier(0);                                        \
    asm volatile("" ::: "memory");

#pragma unroll
    for (int c = 0; c < CPB; c += 2) {
        // ---- chunk c -> buf0 (regs A); pfB + future pfA stay in flight ----
        // compiler auto-inserts counted vmcnt for pfA only (pfB newer, unwaited)
        xs4[0][tid] = pfA0; xs4[0][512 + tid] = pfA1; xs4[0][i2] = pfA2;
        if (c + 2 < CPB) {
            const float4* sn = src4 + (c + 2) * CHUNK_F4;
            pfA0 = sn[tid]; pfA1 = sn[512 + tid]; pfA2 = sn[i2];
        }
        RAW_BARRIER();                    // buf0 visible; prefetches fly on
        COMPUTE_CHUNK(0);

        // ---- chunk c+1 -> buf1 (regs B) ----
        xs4[1][tid] = pfB0; xs4[1][512 + tid] = pfB1; xs4[1][i2] = pfB2;
        if (c + 3 < CPB) {
            const float4* sn = src4 + (c + 3) * CHUNK_F4;
            pfB0 = sn[tid]; pfB1 = sn[512 + tid]; pfB2 = sn[i2];
        }
        RAW_BARRIER();                    // buf1 visible
        COMPUTE_CHUNK(1);
    }

    // ---- epilogue: transposed LDS write + 87-thread column reduce ----------
    __syncthreads();   // loop done; nothing useful in flight — full drain OK
    float* red = (float*)xs4[0];
#pragma unroll
    for (int R = 0; R < RPW; ++R) {
        int j = rowbase + R;
        if (j < J) {
#pragma unroll
            for (int ch = 0; ch < CH; ++ch)
                red[lane * JC + j * CH + ch] = acc[R][ch];
        }
    }
    __syncthreads();
    if (tid < JC) {
        float a = 0.f;
#pragma unroll
        for (int L = 0; L < FPC; ++L) a += red[L * JC + tid];
        partials[(size_t)blockIdx.x * JC + tid] = a;
    }
}

// ---- finalize: identical to R18 ---------------------------------------------
__global__ void finalize_kernel(const float* __restrict__ partials,
                                const float* __restrict__ fcW,
                                const float* __restrict__ fcb,
                                float* __restrict__ out) {
    __shared__ float h[JC];
    int b = blockIdx.x, tid = threadIdx.x;
    if (tid < JC) {
        float a = 0.f;
#pragma unroll
        for (int p = 0; p < BPB; ++p)
            a += partials[(size_t)(b * BPB + p) * JC + tid];
        a *= (1.0f / (float)T);
        h[tid] = a;
        out[(size_t)b * JC + tid] = a;
    }
    __syncthreads();
    if (tid < 2) {
        float a = fcb[tid];
        for (int r = 0; r < JC; ++r) a += h[r] * fcW[r * 2 + tid];
        out[(size_t)B * JC + b * 2 + tid] = 1.0f / (1.0f + expf(-a));
    }
}

extern "C" void kernel_launch(void* const* d_in, const int* in_sizes, int n_in,
                              void* d_out, int out_size, void* d_ws, size_t ws_size,
                              hipStream_t stream) {
    const float* x   = (const float*)d_in[0];
    const int*   ei  = (const int*)d_in[1];
    const float* W   = (const float*)d_in[4];
    const float* bb  = (const float*)d_in[5];
    const float* fcW = (const float*)d_in[6];
    const float* fcb = (const float*)d_in[7];

    char* ws = (char*)d_ws;
    int2* pairs    = (int2*)ws;
    int2* ov_pairs = pairs + PROWS * SLOTS;
    int*  ov_rp    = (int*)(ov_pairs + MAXOV);
    float* partials = (float*)(ws + 4096);            // 1024*87 floats

    prep_kernel<<<1, 64, 0, stream>>>(ei, pairs, ov_rp, ov_pairs);
    gcn_main<<<NBLK, WAVES * 64, 0, stream>>>(x, W, bb, pairs, ov_rp, ov_pairs, partials);
    finalize_kernel<<<B, 128, 0, stream>>>(partials, fcW, fcb, (float*)d_out);
}